// Round 2
// baseline (178.991 us; speedup 1.0000x reference)
//
#include <hip/hip_runtime.h>

#define MUL 16
#define NTILE 30          // 12 s-tiles + 12 pq-tiles + 6 t-tiles
#define NCHUNK 6

typedef __bf16 bf16x8 __attribute__((ext_vector_type(8)));
typedef float  f32x2  __attribute__((ext_vector_type(2)));
typedef float  f32x4  __attribute__((ext_vector_type(4)));

// Group schedule: 24 groups g, each = (u_g, vstart_g), covering 8 pair slots
// j=0..7 with v = vstart+j (valid while v<=15; pads have zero B columns).
//   u<=7: two groups: g=2u+h -> vstart = u + 8h
//   u>=8: one group:  g=16+(u-8) -> vstart = u
// Group g -> chunk c=g>>2, q-lane-group q=g&3.  Every pair (u<=v) appears
// exactly once.
__device__ __forceinline__ void group_uvs(int g, int& u, int& vs) {
    if (g < 16) { u = g >> 1; vs = u + ((g & 1) << 3); }
    else        { u = g - 8;  vs = u; }
}

// ---------------------------------------------------------------------------
// prep: one thread per 16-B B-fragment (tile,lane).
//   s  tiles 2c+h   : group 4c+q, pair j=4h+i -> elem 2i (f000), 2i+1 (f110)
//   pq tiles 12+2c+h: group 4c+q, pair j=4h+i -> elem 2i (fuv),  2i+1 (fvu)
//   t  tiles 24+c   : group 4c+q, pair j=e    -> elem e  (f112)
// ---------------------------------------------------------------------------
__global__ void prep_weights(const float* __restrict__ w000,
                             const float* __restrict__ w101,
                             const float* __restrict__ w110,
                             const float* __restrict__ w112,
                             __bf16* __restrict__ wt) {
    const int gid = blockIdx.x * 256 + threadIdx.x;
    if (gid >= NTILE * 64) return;
    const int T = gid >> 6, lane = gid & 63;
    const int q = lane >> 4, w = lane & 15;

    const float A000   = 0.044194173824159216f;   // sqrt(1/(2*16*16))
    const float A110   = 0.025515518153991442f;   // A000/sqrt(3)
    const float A101   = 0.0625f;
    const float A112C1 = 0.044194173824159216f;   // A112/sqrt(10)

    bf16x8 frag = {};
    if (T < 12) {
        const int c = T >> 1, h = T & 1;
        int u, vs; group_uvs(4 * c + q, u, vs);
#pragma unroll
        for (int i = 0; i < 4; ++i) {
            const int v = vs + 4 * h + i;
            if (v < 16) {
                const int uvw = (u * MUL + v) * MUL + w;
                const int vuw = (v * MUL + u) * MUL + w;
                float f000, f110;
                if (u == v) { f000 = A000 * w000[uvw]; f110 = A110 * w110[uvw]; }
                else        { f000 = A000 * (w000[uvw] + w000[vuw]);
                              f110 = A110 * (w110[uvw] + w110[vuw]); }
                frag[2 * i]     = (__bf16)f000;
                frag[2 * i + 1] = (__bf16)f110;
            }
        }
    } else if (T < 24) {
        const int c = (T - 12) >> 1, h = (T - 12) & 1;
        int u, vs; group_uvs(4 * c + q, u, vs);
#pragma unroll
        for (int i = 0; i < 4; ++i) {
            const int v = vs + 4 * h + i;
            if (v < 16) {
                const int uvw = (u * MUL + v) * MUL + w;
                const int vuw = (v * MUL + u) * MUL + w;
                frag[2 * i]     = (__bf16)(A101 * w101[uvw]);
                frag[2 * i + 1] = (__bf16)((u == v) ? 0.f : A101 * w101[vuw]);
            }
        }
    } else {
        const int c = T - 24;
        int u, vs; group_uvs(4 * c + q, u, vs);
#pragma unroll
        for (int e = 0; e < 8; ++e) {
            const int v = vs + e;
            if (v < 16) {
                const int uvw = (u * MUL + v) * MUL + w;
                const int vuw = (v * MUL + u) * MUL + w;
                const float f112 = (u == v) ? A112C1 * w112[uvw]
                                            : A112C1 * (w112[uvw] + w112[vuw]);
                frag[e] = (__bf16)f112;
            }
        }
    }
    ((bf16x8*)wt)[T * 64 + lane] = frag;
}

// ---------------------------------------------------------------------------
// Main: ONE WAVE per block, 16 nodes, no inter-wave coupling.
// Lane (m=lane&15, q=lane>>4): node m, k-slots [8q,8q+8).  Per chunk the
// lane's 8 pairs share u (read xu ONCE); v = min(vs+J,15).  Products are
// grouped as even-aligned float2 ops -> v_pk_mul_f32.
// ---------------------------------------------------------------------------
#define SQ3f  1.7320508075688772f
#define ISQ3f 0.5773502691896258f

template<int J>
__device__ __forceinline__ void do_pair(int vs, const float* __restrict__ xrow,
        const float4 xu,
        bf16x8& fS, bf16x8& f0, bf16x8& f1, bf16x8& f2,
        bf16x8& t0, bf16x8& t1, bf16x8& t2, bf16x8& t3, bf16x8& t4) {
    int v = vs + J;
    v = v < 15 ? v : 15;                              // pads: B cols are zero
    const float4 xv = *(const float4*)(xrow + 4 * v);

    const f32x2 U01 = {xu.x, xu.y};   // (x0u, a0u)
    const f32x2 U23 = {xu.z, xu.w};   // (a1u, a2u)
    const f32x2 U10 = {xu.y, xu.x};
    const f32x2 V01 = {xv.x, xv.y};
    const f32x2 V23 = {xv.z, xv.w};
    const f32x2 V10 = {xv.y, xv.x};
    const f32x2 V32 = {xv.w, xv.z};

    const f32x2 P1 = U01 * V01;       // (s0,   o00)
    const f32x2 P2 = U23 * V23;       // (o11,  o22)
    const f32x2 P3 = U01 * V23;       // (f1vu, o02)
    const f32x2 P4 = U23 * V01;       // (f1uv, o20)
    const f32x2 P5 = U01 * V32;       // (f2vu, o01)
    const f32x2 P6 = U23 * V10;       // (o10,  f2uv)
    const f32x2 P7 = U23 * V32;       // (o12,  o21)
    const f32x2 P8 = U10 * V01;       // (f0uv, f0vu)

    const float o00 = P1[1], o11 = P2[0], o22 = P2[1];
    const float s1 = (o00 + o11) + o22;

    constexpr int s2 = (J & 3) * 2;
    fS[s2]     = (__bf16)P1[0];  fS[s2 + 1] = (__bf16)s1;
    f0[s2]     = (__bf16)P8[0];  f0[s2 + 1] = (__bf16)P8[1];
    f1[s2]     = (__bf16)P4[0];  f1[s2 + 1] = (__bf16)P3[0];
    f2[s2]     = (__bf16)P6[1];  f2[s2 + 1] = (__bf16)P5[0];
    t0[J] = (__bf16)(P5[1] + P6[0]);
    t1[J] = (__bf16)(P3[1] + P4[1]);
    t2[J] = (__bf16)(P7[0] + P7[1]);
    t3[J] = (__bf16)(o00 - o11);
    t4[J] = (__bf16)(SQ3f * o22 - ISQ3f * s1);
}

__launch_bounds__(64, 4)
__global__ void tsq_kernel(const float* __restrict__ feats,
                           const float* __restrict__ msgs,
                           const __bf16* __restrict__ wtiles,
                           float* __restrict__ out) {
    // quads (x0[u], x1[u][0..2]) per node; node stride 68 dwords (68%32==4)
    __shared__ __align__(16) float xq[16 * 68];        // 4352 B

    const int tid = threadIdx.x;
    const long long blockNode = (long long)blockIdx.x * 16;

    // coalesced load of feats+msgs (16 nodes x 64 f32), scatter to quad layout
    {
        const float4* f4p = (const float4*)(feats + blockNode * 64);
        const float4* m4p = (const float4*)(msgs  + blockNode * 64);
#pragma unroll
        for (int r = 0; r < 4; ++r) {
            const int li = r * 64 + tid;               // 0..255
            const int nd = li >> 4, f4 = li & 15;
            const float4 a = f4p[li];
            const float4 b = m4p[li];
            const float vals[4] = {a.x + b.x, a.y + b.y, a.z + b.z, a.w + b.w};
#pragma unroll
            for (int jj = 0; jj < 4; ++jj) {
                const int f = 4 * f4 + jj;
                int dst;
                if (f < 16) dst = nd * 68 + 4 * f;
                else {
                    const int g = f - 16;
                    const int v3 = (g * 171) >> 9;     // g/3 for g<48
                    dst = nd * 68 + 4 * v3 + 1 + (g - 3 * v3);
                }
                xq[dst] = vals[jj];
            }
        }
    }
    __syncthreads();   // single wave: effectively just a waitcnt

    const int lane = tid;
    const int m = lane & 15, q = lane >> 4;
    const float* xrow = xq + m * 68;
    const bf16x8* wb = (const bf16x8*)wtiles;

    f32x4 accS  = {0.f, 0.f, 0.f, 0.f};
    f32x4 accP0 = {0.f, 0.f, 0.f, 0.f};
    f32x4 accP1 = {0.f, 0.f, 0.f, 0.f};
    f32x4 accP2 = {0.f, 0.f, 0.f, 0.f};
    f32x4 accT0 = {0.f, 0.f, 0.f, 0.f};
    f32x4 accT1 = {0.f, 0.f, 0.f, 0.f};
    f32x4 accT2 = {0.f, 0.f, 0.f, 0.f};
    f32x4 accT3 = {0.f, 0.f, 0.f, 0.f};
    f32x4 accT4 = {0.f, 0.f, 0.f, 0.f};

#pragma unroll
    for (int c = 0; c < NCHUNK; ++c) {
        // group g = 4c+q; c is a compile-time constant -> branch folds
        int u, vs;
        if (c < 4) { u = 2 * c + (q >> 1); vs = u + ((q & 1) << 3); }
        else       { u = 4 * c - 8 + q;    vs = u; }
        const float4 xu = *(const float4*)(xrow + 4 * u);   // ONE read/chunk

        const bf16x8 bS0 = wb[(2 * c) * 64 + lane];
        const bf16x8 bS1 = wb[(2 * c + 1) * 64 + lane];
        const bf16x8 bP0 = wb[(12 + 2 * c) * 64 + lane];
        const bf16x8 bP1 = wb[(13 + 2 * c) * 64 + lane];
        const bf16x8 bT  = wb[(24 + c) * 64 + lane];

        bf16x8 t0 = {}, t1 = {}, t2 = {}, t3 = {}, t4 = {};
        {
            bf16x8 fS, f0, f1, f2;
            do_pair<0>(vs, xrow, xu, fS, f0, f1, f2, t0, t1, t2, t3, t4);
            do_pair<1>(vs, xrow, xu, fS, f0, f1, f2, t0, t1, t2, t3, t4);
            do_pair<2>(vs, xrow, xu, fS, f0, f1, f2, t0, t1, t2, t3, t4);
            do_pair<3>(vs, xrow, xu, fS, f0, f1, f2, t0, t1, t2, t3, t4);
            accS  = __builtin_amdgcn_mfma_f32_16x16x32_bf16(fS, bS0, accS,  0, 0, 0);
            accP0 = __builtin_amdgcn_mfma_f32_16x16x32_bf16(f0, bP0, accP0, 0, 0, 0);
            accP1 = __builtin_amdgcn_mfma_f32_16x16x32_bf16(f1, bP0, accP1, 0, 0, 0);
            accP2 = __builtin_amdgcn_mfma_f32_16x16x32_bf16(f2, bP0, accP2, 0, 0, 0);
        }
        {
            bf16x8 fS, f0, f1, f2;
            do_pair<4>(vs, xrow, xu, fS, f0, f1, f2, t0, t1, t2, t3, t4);
            do_pair<5>(vs, xrow, xu, fS, f0, f1, f2, t0, t1, t2, t3, t4);
            do_pair<6>(vs, xrow, xu, fS, f0, f1, f2, t0, t1, t2, t3, t4);
            do_pair<7>(vs, xrow, xu, fS, f0, f1, f2, t0, t1, t2, t3, t4);
            accS  = __builtin_amdgcn_mfma_f32_16x16x32_bf16(fS, bS1, accS,  0, 0, 0);
            accP0 = __builtin_amdgcn_mfma_f32_16x16x32_bf16(f0, bP1, accP0, 0, 0, 0);
            accP1 = __builtin_amdgcn_mfma_f32_16x16x32_bf16(f1, bP1, accP1, 0, 0, 0);
            accP2 = __builtin_amdgcn_mfma_f32_16x16x32_bf16(f2, bP1, accP2, 0, 0, 0);
        }
        accT0 = __builtin_amdgcn_mfma_f32_16x16x32_bf16(t0, bT, accT0, 0, 0, 0);
        accT1 = __builtin_amdgcn_mfma_f32_16x16x32_bf16(t1, bT, accT1, 0, 0, 0);
        accT2 = __builtin_amdgcn_mfma_f32_16x16x32_bf16(t2, bT, accT2, 0, 0, 0);
        accT3 = __builtin_amdgcn_mfma_f32_16x16x32_bf16(t3, bT, accT3, 0, 0, 0);
        accT4 = __builtin_amdgcn_mfma_f32_16x16x32_bf16(t4, bT, accT4, 0, 0, 0);
    }

    // epilogue: C/D col = lane&15 = output idx w, row = q*4+r = node
#pragma unroll
    for (int r = 0; r < 4; ++r) {
        float* ob = out + (blockNode + q * 4 + r) * 144;
        ob[m]              = accS[r];
        ob[16 + 3 * m + 0] = accP0[r];
        ob[16 + 3 * m + 1] = accP1[r];
        ob[16 + 3 * m + 2] = accP2[r];
        ob[64 + 5 * m + 0] = accT0[r];
        ob[64 + 5 * m + 1] = accT1[r];
        ob[64 + 5 * m + 2] = accT2[r];
        ob[64 + 5 * m + 3] = accT3[r];
        ob[64 + 5 * m + 4] = accT4[r];
    }
}

extern "C" void kernel_launch(void* const* d_in, const int* in_sizes, int n_in,
                              void* d_out, int out_size, void* d_ws, size_t ws_size,
                              hipStream_t stream) {
    const float* feats = (const float*)d_in[0];
    const float* msgs  = (const float*)d_in[1];
    const float* w000  = (const float*)d_in[2];
    const float* w101  = (const float*)d_in[3];
    const float* w110  = (const float*)d_in[4];
    const float* w112  = (const float*)d_in[5];
    __bf16* wt = (__bf16*)d_ws;                 // 30*64*16 B = 30720 B
    float* out = (float*)d_out;

    const int n = in_sizes[0] / (4 * MUL);      // 131072 nodes

    prep_weights<<<(NTILE * 64 + 255) / 256, 256, 0, stream>>>(w000, w101, w110, w112, wt);
    tsq_kernel<<<n / 16, 64, 0, stream>>>(feats, msgs, wt, out);
}

// Round 4
// 153.945 us; speedup vs baseline: 1.1627x; 1.1627x over previous
//
#include <hip/hip_runtime.h>

#define MUL 16
#define NTILE 30          // 12 s-tiles + 12 pq-tiles + 6 t-tiles
#define NCHUNK 6

typedef __bf16 bf16x8 __attribute__((ext_vector_type(8)));
typedef float  f32x2  __attribute__((ext_vector_type(2)));
typedef float  f32x4  __attribute__((ext_vector_type(4)));

// Group schedule: 24 groups g, each = (u_g, vstart_g), covering 8 pair slots
// j=0..7 with v = vstart+j (valid while v<=15; pads have zero B columns).
//   u<=7: two groups: g=2u+h -> vstart = u + 8h
//   u>=8: one group:  g=16+(u-8) -> vstart = u
// Group g -> chunk c=g>>2, q-lane-group q=g&3.
__device__ __forceinline__ void group_uvs(int g, int& u, int& vs) {
    if (g < 16) { u = g >> 1; vs = u + ((g & 1) << 3); }
    else        { u = g - 8;  vs = u; }
}

// ---------------------------------------------------------------------------
// prep: one thread per 16-B B-fragment (tile,lane).
// ---------------------------------------------------------------------------
__global__ void prep_weights(const float* __restrict__ w000,
                             const float* __restrict__ w101,
                             const float* __restrict__ w110,
                             const float* __restrict__ w112,
                             __bf16* __restrict__ wt) {
    const int gid = blockIdx.x * 256 + threadIdx.x;
    if (gid >= NTILE * 64) return;
    const int T = gid >> 6, lane = gid & 63;
    const int q = lane >> 4, w = lane & 15;

    const float A000   = 0.044194173824159216f;   // sqrt(1/(2*16*16))
    const float A110   = 0.025515518153991442f;   // A000/sqrt(3)
    const float A101   = 0.0625f;
    const float A112C1 = 0.044194173824159216f;   // A112/sqrt(10)

    bf16x8 frag = {};
    if (T < 12) {
        const int c = T >> 1, h = T & 1;
        int u, vs; group_uvs(4 * c + q, u, vs);
#pragma unroll
        for (int i = 0; i < 4; ++i) {
            const int v = vs + 4 * h + i;
            if (v < 16) {
                const int uvw = (u * MUL + v) * MUL + w;
                const int vuw = (v * MUL + u) * MUL + w;
                float f000, f110;
                if (u == v) { f000 = A000 * w000[uvw]; f110 = A110 * w110[uvw]; }
                else        { f000 = A000 * (w000[uvw] + w000[vuw]);
                              f110 = A110 * (w110[uvw] + w110[vuw]); }
                frag[2 * i]     = (__bf16)f000;
                frag[2 * i + 1] = (__bf16)f110;
            }
        }
    } else if (T < 24) {
        const int c = (T - 12) >> 1, h = (T - 12) & 1;
        int u, vs; group_uvs(4 * c + q, u, vs);
#pragma unroll
        for (int i = 0; i < 4; ++i) {
            const int v = vs + 4 * h + i;
            if (v < 16) {
                const int uvw = (u * MUL + v) * MUL + w;
                const int vuw = (v * MUL + u) * MUL + w;
                frag[2 * i]     = (__bf16)(A101 * w101[uvw]);
                frag[2 * i + 1] = (__bf16)((u == v) ? 0.f : A101 * w101[vuw]);
            }
        }
    } else {
        const int c = T - 24;
        int u, vs; group_uvs(4 * c + q, u, vs);
#pragma unroll
        for (int e = 0; e < 8; ++e) {
            const int v = vs + e;
            if (v < 16) {
                const int uvw = (u * MUL + v) * MUL + w;
                const int vuw = (v * MUL + u) * MUL + w;
                const float f112 = (u == v) ? A112C1 * w112[uvw]
                                            : A112C1 * (w112[uvw] + w112[vuw]);
                frag[e] = (__bf16)f112;
            }
        }
    }
    ((bf16x8*)wt)[T * 64 + lane] = frag;
}

// ---------------------------------------------------------------------------
// Main: ONE WAVE per block, 16 nodes.  r2 schedule plus:
//  - one-chunk-ahead prefetch of B-fragments (hide L2 latency)
//  - LDS-transposed epilogue: 9 coalesced dwordx4 stores instead of 36
//    scattered dword stores (targets the 1.9x WRITE_SIZE inflation)
// ---------------------------------------------------------------------------
#define SQ3f  1.7320508075688772f
#define ISQ3f 0.5773502691896258f

template<int J>
__device__ __forceinline__ void do_pair(int vs, const float* __restrict__ xrow,
        const float4 xu,
        bf16x8& fS, bf16x8& f0, bf16x8& f1, bf16x8& f2,
        bf16x8& t0, bf16x8& t1, bf16x8& t2, bf16x8& t3, bf16x8& t4) {
    int v = vs + J;
    v = v < 15 ? v : 15;                              // pads: B cols are zero
    const float4 xv = *(const float4*)(xrow + 4 * v);

    const f32x2 U01 = {xu.x, xu.y};   // (x0u, a0u)
    const f32x2 U23 = {xu.z, xu.w};   // (a1u, a2u)
    const f32x2 U10 = {xu.y, xu.x};
    const f32x2 V01 = {xv.x, xv.y};
    const f32x2 V23 = {xv.z, xv.w};
    const f32x2 V10 = {xv.y, xv.x};
    const f32x2 V32 = {xv.w, xv.z};

    const f32x2 P1 = U01 * V01;       // (s0,   o00)
    const f32x2 P2 = U23 * V23;       // (o11,  o22)
    const f32x2 P3 = U01 * V23;       // (f1vu, o02)
    const f32x2 P4 = U23 * V01;       // (f1uv, o20)
    const f32x2 P5 = U01 * V32;       // (f2vu, o01)
    const f32x2 P6 = U23 * V10;       // (o10,  f2uv)
    const f32x2 P7 = U23 * V32;       // (o12,  o21)
    const f32x2 P8 = U10 * V01;       // (f0uv, f0vu)

    const float o00 = P1[1], o11 = P2[0], o22 = P2[1];
    const float s1 = (o00 + o11) + o22;

    constexpr int s2 = (J & 3) * 2;
    fS[s2]     = (__bf16)P1[0];  fS[s2 + 1] = (__bf16)s1;
    f0[s2]     = (__bf16)P8[0];  f0[s2 + 1] = (__bf16)P8[1];
    f1[s2]     = (__bf16)P4[0];  f1[s2 + 1] = (__bf16)P3[0];
    f2[s2]     = (__bf16)P6[1];  f2[s2 + 1] = (__bf16)P5[0];
    t0[J] = (__bf16)(P5[1] + P6[0]);
    t1[J] = (__bf16)(P3[1] + P4[1]);
    t2[J] = (__bf16)(P7[0] + P7[1]);
    t3[J] = (__bf16)(o00 - o11);
    t4[J] = (__bf16)(SQ3f * o22 - ISQ3f * s1);
}

__launch_bounds__(64, 4)
__global__ void tsq_kernel(const float* __restrict__ feats,
                           const float* __restrict__ msgs,
                           const __bf16* __restrict__ wtiles,
                           float* __restrict__ out) {
    // quads (x0[u], x1[u][0..2]) per node; node stride 68 dwords (68%32==4)
    __shared__ __align__(16) float xq[16 * 68];        // 4352 B
    __shared__ __align__(16) float ep[16 * 144];       // 9216 B epilogue image

    const int tid = threadIdx.x;
    const long long blockNode = (long long)blockIdx.x * 16;

    // coalesced load of feats+msgs (16 nodes x 64 f32), scatter to quad layout
    {
        const float4* f4p = (const float4*)(feats + blockNode * 64);
        const float4* m4p = (const float4*)(msgs  + blockNode * 64);
#pragma unroll
        for (int r = 0; r < 4; ++r) {
            const int li = r * 64 + tid;               // 0..255
            const int nd = li >> 4, f4 = li & 15;
            const float4 a = f4p[li];
            const float4 b = m4p[li];
            const float vals[4] = {a.x + b.x, a.y + b.y, a.z + b.z, a.w + b.w};
#pragma unroll
            for (int jj = 0; jj < 4; ++jj) {
                const int f = 4 * f4 + jj;
                int dst;
                if (f < 16) dst = nd * 68 + 4 * f;
                else {
                    const int g = f - 16;
                    const int v3 = (g * 171) >> 9;     // g/3 for g<48
                    dst = nd * 68 + 4 * v3 + 1 + (g - 3 * v3);
                }
                xq[dst] = vals[jj];
            }
        }
    }
    __syncthreads();   // single wave: cheap

    const int lane = tid;
    const int m = lane & 15, q = lane >> 4;
    const float* xrow = xq + m * 68;
    const bf16x8* wb = (const bf16x8*)wtiles;

    f32x4 accS  = {0.f, 0.f, 0.f, 0.f};
    f32x4 accP0 = {0.f, 0.f, 0.f, 0.f};
    f32x4 accP1 = {0.f, 0.f, 0.f, 0.f};
    f32x4 accP2 = {0.f, 0.f, 0.f, 0.f};
    f32x4 accT0 = {0.f, 0.f, 0.f, 0.f};
    f32x4 accT1 = {0.f, 0.f, 0.f, 0.f};
    f32x4 accT2 = {0.f, 0.f, 0.f, 0.f};
    f32x4 accT3 = {0.f, 0.f, 0.f, 0.f};
    f32x4 accT4 = {0.f, 0.f, 0.f, 0.f};

    // prefetch chunk 0's B-fragments
    bf16x8 bS0 = wb[0 * 64 + lane];
    bf16x8 bS1 = wb[1 * 64 + lane];
    bf16x8 bP0 = wb[12 * 64 + lane];
    bf16x8 bP1 = wb[13 * 64 + lane];
    bf16x8 bT  = wb[24 * 64 + lane];

#pragma unroll
    for (int c = 0; c < NCHUNK; ++c) {
        // issue next chunk's fragment loads first (hide L2 latency)
        bf16x8 nS0 = {}, nS1 = {}, nP0 = {}, nP1 = {}, nT = {};
        if (c + 1 < NCHUNK) {
            nS0 = wb[(2 * c + 2) * 64 + lane];
            nS1 = wb[(2 * c + 3) * 64 + lane];
            nP0 = wb[(14 + 2 * c) * 64 + lane];
            nP1 = wb[(15 + 2 * c) * 64 + lane];
            nT  = wb[(25 + c) * 64 + lane];
        }

        // group g = 4c+q; c is compile-time -> folds
        int u, vs;
        if (c < 4) { u = 2 * c + (q >> 1); vs = u + ((q & 1) << 3); }
        else       { u = 4 * c - 8 + q;    vs = u; }
        const float4 xu = *(const float4*)(xrow + 4 * u);   // ONE read/chunk

        bf16x8 t0 = {}, t1 = {}, t2 = {}, t3 = {}, t4 = {};
        {
            bf16x8 fS, f0, f1, f2;
            do_pair<0>(vs, xrow, xu, fS, f0, f1, f2, t0, t1, t2, t3, t4);
            do_pair<1>(vs, xrow, xu, fS, f0, f1, f2, t0, t1, t2, t3, t4);
            do_pair<2>(vs, xrow, xu, fS, f0, f1, f2, t0, t1, t2, t3, t4);
            do_pair<3>(vs, xrow, xu, fS, f0, f1, f2, t0, t1, t2, t3, t4);
            accS  = __builtin_amdgcn_mfma_f32_16x16x32_bf16(fS, bS0, accS,  0, 0, 0);
            accP0 = __builtin_amdgcn_mfma_f32_16x16x32_bf16(f0, bP0, accP0, 0, 0, 0);
            accP1 = __builtin_amdgcn_mfma_f32_16x16x32_bf16(f1, bP0, accP1, 0, 0, 0);
            accP2 = __builtin_amdgcn_mfma_f32_16x16x32_bf16(f2, bP0, accP2, 0, 0, 0);
        }
        {
            bf16x8 fS, f0, f1, f2;
            do_pair<4>(vs, xrow, xu, fS, f0, f1, f2, t0, t1, t2, t3, t4);
            do_pair<5>(vs, xrow, xu, fS, f0, f1, f2, t0, t1, t2, t3, t4);
            do_pair<6>(vs, xrow, xu, fS, f0, f1, f2, t0, t1, t2, t3, t4);
            do_pair<7>(vs, xrow, xu, fS, f0, f1, f2, t0, t1, t2, t3, t4);
            accS  = __builtin_amdgcn_mfma_f32_16x16x32_bf16(fS, bS1, accS,  0, 0, 0);
            accP0 = __builtin_amdgcn_mfma_f32_16x16x32_bf16(f0, bP1, accP0, 0, 0, 0);
            accP1 = __builtin_amdgcn_mfma_f32_16x16x32_bf16(f1, bP1, accP1, 0, 0, 0);
            accP2 = __builtin_amdgcn_mfma_f32_16x16x32_bf16(f2, bP1, accP2, 0, 0, 0);
        }
        accT0 = __builtin_amdgcn_mfma_f32_16x16x32_bf16(t0, bT, accT0, 0, 0, 0);
        accT1 = __builtin_amdgcn_mfma_f32_16x16x32_bf16(t1, bT, accT1, 0, 0, 0);
        accT2 = __builtin_amdgcn_mfma_f32_16x16x32_bf16(t2, bT, accT2, 0, 0, 0);
        accT3 = __builtin_amdgcn_mfma_f32_16x16x32_bf16(t3, bT, accT3, 0, 0, 0);
        accT4 = __builtin_amdgcn_mfma_f32_16x16x32_bf16(t4, bT, accT4, 0, 0, 0);

        bS0 = nS0; bS1 = nS1; bP0 = nP0; bP1 = nP1; bT = nT;
    }

    // ---- epilogue: scatter to LDS image, then coalesced dwordx4 write-out ----
    // C/D col = lane&15 = output idx w, row = q*4+r = node-in-block
#pragma unroll
    for (int r = 0; r < 4; ++r) {
        float* eb = ep + (q * 4 + r) * 144;
        eb[m]              = accS[r];
        eb[16 + 3 * m + 0] = accP0[r];
        eb[16 + 3 * m + 1] = accP1[r];
        eb[16 + 3 * m + 2] = accP2[r];
        eb[64 + 5 * m + 0] = accT0[r];
        eb[64 + 5 * m + 1] = accT1[r];
        eb[64 + 5 * m + 2] = accT2[r];
        eb[64 + 5 * m + 3] = accT3[r];
        eb[64 + 5 * m + 4] = accT4[r];
    }
    __syncthreads();   // order LDS scatter before read-back (1 wave: cheap)

    {
        const float4* ep4 = (const float4*)ep;
        float4* ob4 = (float4*)(out + blockNode * 144);
#pragma unroll
        for (int l = 0; l < 9; ++l)
            ob4[l * 64 + lane] = ep4[l * 64 + lane];   // 1024 B/instr contiguous
    }
}

extern "C" void kernel_launch(void* const* d_in, const int* in_sizes, int n_in,
                              void* d_out, int out_size, void* d_ws, size_t ws_size,
                              hipStream_t stream) {
    const float* feats = (const float*)d_in[0];
    const float* msgs  = (const float*)d_in[1];
    const float* w000  = (const float*)d_in[2];
    const float* w101  = (const float*)d_in[3];
    const float* w110  = (const float*)d_in[4];
    const float* w112  = (const float*)d_in[5];
    __bf16* wt = (__bf16*)d_ws;                 // 30*64*16 B = 30720 B
    float* out = (float*)d_out;

    const int n = in_sizes[0] / (4 * MUL);      // 131072 nodes

    prep_weights<<<(NTILE * 64 + 255) / 256, 256, 0, stream>>>(w000, w101, w110, w112, wt);
    tsq_kernel<<<n / 16, 64, 0, stream>>>(feats, msgs, wt, out);
}